// Round 5
// baseline (6608.468 us; speedup 1.0000x reference)
//
#include <hip/hip_runtime.h>

// MultiHeadAttention: B=2, T=2048, C=1024, H=16, Dh=64, causal, scale = C^-0.5 = 1/32.
// FP32 END-TO-END I/O (R4 post-mortem: inputs proven fp32 by device probe; the
// "(bf16" in the harness error label is a hardcoded f-string — output dtype is
// the reference's, i.e. fp32. R3/R4 byte-identical error proved compute was
// self-consistent; only the output encoding was wrong.)
// ALL-SCALAR anchor build: no MFMA, no LDS. fp32 accumulation; Q/K/V/attn
// intermediates bf16 (2% threshold). ws footprint: 32 MB.
//
//   1. qkv_scalar:  Q,K,V (B,H,T,Dh) bf16
//   2. attn_scalar: one wave per (b,h,t) row, online softmax, lane = d
//   3. proj_scalar: attn (B*T,C) @ w_proj + bias -> out (fp32)

typedef unsigned short u16;
typedef unsigned int u32;

#define T_SEQ 2048
#define C_DIM 1024
#define H_NUM 16
#define D_HEAD 64

static __device__ inline short f2bf(float f) {
  union { float f; u32 u; } v; v.f = f;
  u32 u = v.u;
  return (short)((u + 0x7FFFu + ((u >> 16) & 1u)) >> 16);
}

static __device__ inline float bf2f(short s) {
  union { u32 u; float f; } v; v.u = ((u32)(u16)s) << 16;
  return v.f;
}

// ---------------------------------------------------------------------------
// Kernel 1: QKV projection, scalar. grid 6144 x 256.
// block -> (sel, b, h, 32-row t-block); thread: d = tid&63 (coalesced on w),
// 8 t-rows per thread reuse each weight load 8x.
__global__ __launch_bounds__(256) void qkv_scalar(
    const float* __restrict__ x, const float* __restrict__ wq,
    const float* __restrict__ wk, const float* __restrict__ wv,
    short* __restrict__ qb, short* __restrict__ kb, short* __restrict__ vb) {
  const int combo = blockIdx.x >> 6;           // 0..95 = sel*32 + b*16 + h
  const int sel = combo >> 5;                  // 0..2
  const int b   = (combo >> 4) & 1;
  const int h   = combo & 15;
  const int tb  = (blockIdx.x & 63) * 32;
  const int d   = threadIdx.x & 63;
  const int t0  = tb + (threadIdx.x >> 6) * 8;

  const float* w  = (sel == 0) ? wq : (sel == 1) ? wk : wv;  // (H,C,Dh)
  const float* wp = w + (size_t)h * (C_DIM * D_HEAD) + d;
  const float* xp = x + ((size_t)b * T_SEQ + t0) * C_DIM;

  float acc[8] = {0.f, 0.f, 0.f, 0.f, 0.f, 0.f, 0.f, 0.f};
  for (int c = 0; c < C_DIM; c++) {
    float wv_ = wp[(size_t)c * D_HEAD];        // lanes d coalesced, 256B/wave
#pragma unroll
    for (int i = 0; i < 8; i++)
      acc[i] += wv_ * xp[(size_t)i * C_DIM + c];   // wave-uniform broadcast
  }

  short* outp = (sel == 0) ? qb : (sel == 1) ? kb : vb;   // (B,H,T,Dh)
  size_t base = ((size_t)(b * H_NUM + h) * T_SEQ + t0) * D_HEAD + d;
#pragma unroll
  for (int i = 0; i < 8; i++)
    outp[base + (size_t)i * D_HEAD] = f2bf(acc[i]);
}

// ---------------------------------------------------------------------------
// Kernel 2: attention, scalar online-softmax. grid 16384 x 256 (4 waves/block).
// One wave per (b,h,t) query row; lane = d. Causal mask = loop bound s <= t.
// Scale folded into q. fp32 state (m, l, o).
__global__ __launch_bounds__(256) void attn_scalar(
    const short* __restrict__ qb, const short* __restrict__ kb,
    const short* __restrict__ vb, short* __restrict__ attnb) {
  const int row = blockIdx.x * 4 + (threadIdx.x >> 6);  // bh*2048 + t
  const int d   = threadIdx.x & 63;
  const int bh  = row >> 11;
  const int t   = row & 2047;
  const short* kp = kb + (size_t)bh * T_SEQ * D_HEAD;
  const short* vp = vb + (size_t)bh * T_SEQ * D_HEAD;

  const float qd = bf2f(qb[((size_t)bh * T_SEQ + t) * D_HEAD + d]) * 0.03125f;

  float m = -1e30f, l = 0.f, o = 0.f;
  for (int s = 0; s <= t; s++) {
    float pr = qd * bf2f(kp[(size_t)s * D_HEAD + d]);
    pr += __shfl_xor(pr, 1);
    pr += __shfl_xor(pr, 2);
    pr += __shfl_xor(pr, 4);
    pr += __shfl_xor(pr, 8);
    pr += __shfl_xor(pr, 16);
    pr += __shfl_xor(pr, 32);                 // full 64-lane dot, broadcast
    float mn = fmaxf(m, pr);
    float p  = __expf(pr - mn);
    float f  = __expf(m - mn);                // m=-1e30 first iter -> f=0
    l = l * f + p;
    m = mn;
    o = o * f + p * bf2f(vp[(size_t)s * D_HEAD + d]);
  }

  const int b = bh >> 4, h = bh & 15;
  attnb[((size_t)(b * T_SEQ + t)) * C_DIM + h * D_HEAD + d] = f2bf(o / l);
}

// ---------------------------------------------------------------------------
// Kernel 3: output projection + bias, scalar, FP32 OUT. grid 2048 x 256.
// block -> (32-row block, 64-col block); thread: n = tid&63 (coalesced on w),
// 8 rows per thread.
__global__ __launch_bounds__(256) void proj_scalar(
    const short* __restrict__ attnb, const float* __restrict__ wp,
    const float* __restrict__ bias, float* __restrict__ out) {
  const int rb = blockIdx.x >> 4;              // 0..127
  const int n  = (blockIdx.x & 15) * 64 + (threadIdx.x & 63);
  const int r0 = rb * 32 + (threadIdx.x >> 6) * 8;

  float acc[8] = {0.f, 0.f, 0.f, 0.f, 0.f, 0.f, 0.f, 0.f};
  for (int k = 0; k < C_DIM; k++) {
    float wv_ = wp[(size_t)k * C_DIM + n];     // lanes n coalesced, 256B/wave
#pragma unroll
    for (int i = 0; i < 8; i++)
      acc[i] += wv_ * bf2f(attnb[(size_t)(r0 + i) * C_DIM + k]);
  }
  float bs = bias[n];
#pragma unroll
  for (int i = 0; i < 8; i++)
    out[(size_t)(r0 + i) * C_DIM + n] = acc[i] + bs;
}

// ---------------------------------------------------------------------------
extern "C" void kernel_launch(void* const* d_in, const int* in_sizes, int n_in,
                              void* d_out, int out_size, void* d_ws, size_t ws_size,
                              hipStream_t stream) {
  const float* x     = (const float*)d_in[0];
  const float* wq    = (const float*)d_in[1];
  const float* wk    = (const float*)d_in[2];
  const float* wv    = (const float*)d_in[3];
  const float* wproj = (const float*)d_in[4];
  const float* bias  = (const float*)d_in[5];

  short* ws = (short*)d_ws;
  // workspace (u16 elements): 16M shorts = 32 MB total
  short* qb    = ws;                    // 4,194,304  (B,H,T,Dh)
  short* kb    = ws + 4194304;          // 4,194,304  (B,H,T,Dh)
  short* vb    = ws + 8388608;          // 4,194,304  (B,H,T,Dh)
  short* attnb = ws + 12582912;         // 4,194,304  (B,T,C)

  qkv_scalar<<<6144, 256, 0, stream>>>(x, wq, wk, wv, qb, kb, vb);
  attn_scalar<<<16384, 256, 0, stream>>>(qb, kb, vb, attnb);
  proj_scalar<<<2048, 256, 0, stream>>>(attnb, wproj, bias, (float*)d_out);
}

// Round 6
// 619.564 us; speedup vs baseline: 10.6663x; 10.6663x over previous
//
#include <hip/hip_runtime.h>

// MultiHeadAttention: B=2, T=2048, C=1024, H=16, Dh=64, causal, scale = C^-0.5 = 1/32.
// FP32 I/O (proven R5). bf16 MFMA pipeline, fp32 accumulation.
//
//   1. ingest: x->xb bf16; wq/wk/wv (H,C,Dh) -> wt (48,Dh,C) bf16; w_proj -> wpT bf16
//   2. qkv:    Q (ws), K (d_out lo), V^T (d_out hi)  [d_out is scratch until proj]
//   3. attn:   flash online softmax, 64 q/block, 16 q/wave, MFMA 16x16x32
//   4. proj:   attnb @ w_proj + bias -> d_out fp32 (overwrites K/V scratch)
//
// ws layout (16M shorts = 32 MB, the R4-proven footprint):
//   wt[0,3M) wpT[3M,4M) qb[4M,8M) attnb[8M,12M) xb[12M,16M)
//
// MFMA fragment layouts (HW-verified, guide §3):
//   A:   lane holds A[m=lane&15][k=quad*8+j], j=0..7   (quad = lane>>4)
//   B:   lane holds B[k=quad*8+j][n=lane&15]
//   C/D: lane holds D[m=quad*4+r][n=lane&15], r=0..3

typedef unsigned short u16;
typedef unsigned int u32;

using bf16x8 = __attribute__((ext_vector_type(8))) short;
using f32x4  = __attribute__((ext_vector_type(4))) float;

#define T_SEQ 2048
#define C_DIM 1024
#define H_NUM 16
#define D_HEAD 64

static __device__ inline f32x4 mfma16(bf16x8 a, bf16x8 b, f32x4 c) {
  return __builtin_amdgcn_mfma_f32_16x16x32_bf16(a, b, c, 0, 0, 0);
}

static __device__ inline short f2bf(float f) {
  union { float f; u32 u; } v; v.f = f;
  u32 u = v.u;
  return (short)((u + 0x7FFFu + ((u >> 16) & 1u)) >> 16);
}

// ---------------------------------------------------------------------------
// Kernel 1: ingest fp32 -> bf16 (+ weight transposes). grid 32768 x 256.
//  ids [0, 4M):   xb[id] = cvt(x[id])
//  ids [4M, 7M):  wq/wk/wv (h,c,d) -> wt[(sel*16+h)*65536 + d*1024 + c]
//  ids [7M, 8M):  w_proj (k,n)     -> wpT[n*1024 + k]
__global__ __launch_bounds__(256) void ingest_kernel(
    const float* __restrict__ x, const float* __restrict__ wq,
    const float* __restrict__ wk, const float* __restrict__ wv,
    const float* __restrict__ wproj,
    short* __restrict__ xb, short* __restrict__ wt, short* __restrict__ wpT) {
  long id = (long)blockIdx.x * 256 + threadIdx.x;
  const long NX = 4194304, NW = 7340032;
  if (id < NX) {
    xb[id] = f2bf(x[id]);
  } else if (id < NW) {
    long t = id - NX;
    int h3 = (int)(t >> 16);          // 0..47  (sel*16 + h)
    int r  = (int)(t & 65535);
    int c  = r & 1023;
    int d  = r >> 10;                 // 0..63
    const float* w = (h3 < 16) ? wq : (h3 < 32) ? wk : wv;
    int h = h3 & 15;
    wt[(size_t)h3 * 65536 + d * 1024 + c] = f2bf(w[(size_t)h * 65536 + c * 64 + d]);
  } else {
    long t = id - NW;
    int k = (int)(t & 1023);
    int n = (int)(t >> 10);
    wpT[(size_t)n * 1024 + k] = f2bf(wproj[(size_t)k * 1024 + n]);
  }
}

// ---------------------------------------------------------------------------
// Kernel 2: QKV projection. grid (64, 48), block 256 (4 waves).
// Block = 64 rows x 64 cols (one head of one of q/k/v). A-frags from xb rows,
// B-frags from wt (both contiguous 16B). V transposed via LDS for coalescing.
__global__ __launch_bounds__(256) void qkv_kernel(
    const short* __restrict__ x, const short* __restrict__ wt,
    short* __restrict__ qo, short* __restrict__ ko, short* __restrict__ vto) {
  const int m0  = blockIdx.x * 64;
  const int by  = blockIdx.y;          // sel*16 + h
  const int tid = threadIdx.x;
  const int wid = tid >> 6;
  const int lane = tid & 63;
  const int l15 = lane & 15, quad = lane >> 4;

  __shared__ __align__(16) short vtile[64 * 65];

  const short* wtp  = wt + (size_t)by * 65536;            // [d][c] layout
  const int  mrow = m0 + wid * 16 + l15;                  // A-frag row
  const short* xrow = x + (size_t)mrow * C_DIM;
  const short* bbase = wtp + (size_t)l15 * C_DIM + quad * 8;

  f32x4 acc[4] = { {0,0,0,0}, {0,0,0,0}, {0,0,0,0}, {0,0,0,0} };

#pragma unroll 4
  for (int kc = 0; kc < C_DIM; kc += 32) {
    bf16x8 a = *(const bf16x8*)(xrow + kc + quad * 8);
#pragma unroll
    for (int c = 0; c < 4; c++) {
      bf16x8 b = *(const bf16x8*)(bbase + (size_t)c * 16 * C_DIM + kc);
      acc[c] = mfma16(a, b, acc[c]);
    }
  }

  const int sel = by >> 4;
  const int h   = by & 15;
  const int b   = m0 >> 11;               // 64-row tiles never straddle b
  const size_t bh = (size_t)(b * H_NUM + h);

  if (sel == 2) {
    // V: stage C-frags in LDS, coalesced transposed store (B,H,Dh,T)
#pragma unroll
    for (int c = 0; c < 4; c++) {
#pragma unroll
      for (int r = 0; r < 4; r++) {
        int ml = wid * 16 + quad * 4 + r;
        vtile[ml * 65 + c * 16 + l15] = f2bf(acc[c][r]);
      }
    }
    __syncthreads();
    int d  = tid >> 2;
    int t0 = (tid & 3) * 16;
    bf16x8 v0, v1;
#pragma unroll
    for (int i = 0; i < 8; i++) {
      v0[i] = vtile[(t0 + i) * 65 + d];
      v1[i] = vtile[(t0 + 8 + i) * 65 + d];
    }
    short* dst = vto + ((bh * D_HEAD + d) * T_SEQ + (m0 & 2047) + t0);
    *(bf16x8*)(dst)     = v0;
    *(bf16x8*)(dst + 8) = v1;
  } else {
    short* outp = (sel == 0) ? qo : ko;   // (B,H,T,Dh)
#pragma unroll
    for (int c = 0; c < 4; c++) {
#pragma unroll
      for (int r = 0; r < 4; r++) {
        int t = (m0 & 2047) + wid * 16 + quad * 4 + r;
        int d = c * 16 + l15;
        outp[(bh * T_SEQ + t) * D_HEAD + d] = f2bf(acc[c][r]);
      }
    }
  }
}

// ---------------------------------------------------------------------------
// Kernel 3: flash attention. grid (32, 16, 2), block 256 (4 waves).
// Wave owns 16 q rows; K/V frags from global (L1/L2-shared). LDS: wave-private
// P C-layout -> A-layout, ordered by __syncthreads (block-uniform trip count).
__global__ __launch_bounds__(256) void attn_kernel(
    const short* __restrict__ q, const short* __restrict__ k,
    const short* __restrict__ vt, short* __restrict__ attn) {
  const int qt = blockIdx.x, h = blockIdx.y, b = blockIdx.z;
  const int q0 = qt * 64;
  const size_t bh = (size_t)(b * H_NUM + h);
  const short* qp = q  + bh * T_SEQ * D_HEAD;
  const short* kp = k  + bh * T_SEQ * D_HEAD;
  const short* vp = vt + bh * D_HEAD * T_SEQ;   // (Dh, T)

  const int tid = threadIdx.x;
  const int wid = tid >> 6;
  const int lane = tid & 63;
  const int l15 = lane & 15, quad = lane >> 4;

  __shared__ __align__(16) short P_lds[4 * 1024];
  short* pw = &P_lds[wid * 1024];

  const int qrow = q0 + wid * 16 + l15;
  bf16x8 qa0 = *(const bf16x8*)(qp + (size_t)qrow * D_HEAD + quad * 8);
  bf16x8 qa1 = *(const bf16x8*)(qp + (size_t)qrow * D_HEAD + quad * 8 + 32);

  f32x4 o[4] = { {0,0,0,0}, {0,0,0,0}, {0,0,0,0}, {0,0,0,0} };
  float m_i[4] = { -1e30f, -1e30f, -1e30f, -1e30f };
  float l_i[4] = { 0.f, 0.f, 0.f, 0.f };
  const float scale = 0.03125f;               // C^-0.5, C = 1024 (full n_embd)
  const int qg_base = q0 + wid * 16 + quad * 4;

#pragma unroll 1
  for (int t = 0; t <= qt; t++) {
    const int s0 = t * 64;

    // S = Q K^T (16 q-rows x 64 keys per wave)
    f32x4 s[4];
#pragma unroll
    for (int c = 0; c < 4; c++) {
      const short* krow = kp + (size_t)(s0 + c * 16 + l15) * D_HEAD + quad * 8;
      bf16x8 kb0 = *(const bf16x8*)(krow);
      bf16x8 kb1 = *(const bf16x8*)(krow + 32);
      f32x4 z = { 0, 0, 0, 0 };
      z = mfma16(qa0, kb0, z);
      z = mfma16(qa1, kb1, z);
      s[c] = z;
    }

    // scale + causal mask + row max (rows in (quad,r); keys in lane&15)
    float rmax[4] = { -1e30f, -1e30f, -1e30f, -1e30f };
#pragma unroll
    for (int c = 0; c < 4; c++) {
      int sg = s0 + c * 16 + l15;
#pragma unroll
      for (int r = 0; r < 4; r++) {
        float v = s[c][r] * scale;
        if (sg > qg_base + r) v = -1e30f;
        s[c][r] = v;
        rmax[r] = fmaxf(rmax[r], v);
      }
    }
#pragma unroll
    for (int r = 0; r < 4; r++) {
      float v = rmax[r];
      v = fmaxf(v, __shfl_xor(v, 1));
      v = fmaxf(v, __shfl_xor(v, 2));
      v = fmaxf(v, __shfl_xor(v, 4));
      v = fmaxf(v, __shfl_xor(v, 8));
      rmax[r] = v;
    }

    float alpha[4], rsum[4];
#pragma unroll
    for (int r = 0; r < 4; r++) {
      float mn = fmaxf(m_i[r], rmax[r]);
      alpha[r] = __expf(m_i[r] - mn);         // exp(-1e30-finite)==0, no NaN
      m_i[r] = mn;
      rsum[r] = 0.f;
    }
#pragma unroll
    for (int c = 0; c < 4; c++) {
#pragma unroll
      for (int r = 0; r < 4; r++) {
        float p = __expf(s[c][r] - m_i[r]);
        s[c][r] = p;
        rsum[r] += p;
      }
    }
#pragma unroll
    for (int r = 0; r < 4; r++) {
      float v = rsum[r];
      v += __shfl_xor(v, 1);
      v += __shfl_xor(v, 2);
      v += __shfl_xor(v, 4);
      v += __shfl_xor(v, 8);
      l_i[r] = l_i[r] * alpha[r] + v;
#pragma unroll
      for (int c = 0; c < 4; c++) o[c][r] *= alpha[r];
    }

    // P: C-layout (q=quad*4+r, key=c*16+l15) -> A-layout in LDS (bf16).
    // Region kh=key>>5 holds lane L: P[q=L&15][key = kh*32 + (L>>4)*8 + j]
#pragma unroll
    for (int c = 0; c < 4; c++) {
      int kh   = c >> 1;
      int hi   = ((c * 2 + (l15 >> 3)) & 3) << 4;   // target lane bits [5:4]
      int j    = l15 & 7;
#pragma unroll
      for (int r = 0; r < 4; r++) {
        int lane_r = (quad * 4 + r) | hi;
        pw[kh * 512 + lane_r * 8 + j] = f2bf(s[c][r]);
      }
    }
    __syncthreads();
    bf16x8 pa0 = *(const bf16x8*)(pw + lane * 8);
    bf16x8 pa1 = *(const bf16x8*)(pw + 512 + lane * 8);
    __syncthreads();

    // O += P V  (V^T rows are d, contiguous in key)
#pragma unroll
    for (int c = 0; c < 4; c++) {
      const short* vrow = vp + (size_t)(c * 16 + l15) * T_SEQ + s0 + quad * 8;
      bf16x8 vb0 = *(const bf16x8*)(vrow);
      bf16x8 vb1 = *(const bf16x8*)(vrow + 32);
      o[c] = mfma16(pa0, vb0, o[c]);
      o[c] = mfma16(pa1, vb1, o[c]);
    }
  }

  // epilogue: divide by l, write concat-head layout (B,T,H*Dh) bf16
#pragma unroll
  for (int r = 0; r < 4; r++) {
    float inv = 1.0f / l_i[r];
    int qg = q0 + wid * 16 + quad * 4 + r;
    size_t rowoff = ((size_t)b * T_SEQ + qg) * C_DIM + h * D_HEAD;
#pragma unroll
    for (int c = 0; c < 4; c++) {
      attn[rowoff + c * 16 + l15] = f2bf(o[c][r] * inv);
    }
  }
}

// ---------------------------------------------------------------------------
// Kernel 4: output projection + fp32 bias -> fp32 out. grid (64, 16).
__global__ __launch_bounds__(256) void proj_kernel(
    const short* __restrict__ a_in, const short* __restrict__ wpT,
    const float* __restrict__ bias, float* __restrict__ out) {
  const int m0 = blockIdx.x * 64, n0 = blockIdx.y * 64;
  const int tid = threadIdx.x;
  const int wid = tid >> 6;
  const int lane = tid & 63;
  const int l15 = lane & 15, quad = lane >> 4;

  const int  mrow = m0 + wid * 16 + l15;
  const short* arow = a_in + (size_t)mrow * C_DIM;
  const short* bbase = wpT + (size_t)(n0 + l15) * C_DIM + quad * 8;

  f32x4 acc[4] = { {0,0,0,0}, {0,0,0,0}, {0,0,0,0}, {0,0,0,0} };

#pragma unroll 4
  for (int kc = 0; kc < C_DIM; kc += 32) {
    bf16x8 a = *(const bf16x8*)(arow + kc + quad * 8);
#pragma unroll
    for (int c = 0; c < 4; c++) {
      bf16x8 b = *(const bf16x8*)(bbase + (size_t)c * 16 * C_DIM + kc);
      acc[c] = mfma16(a, b, acc[c]);
    }
  }

#pragma unroll
  for (int c = 0; c < 4; c++) {
    int n = n0 + c * 16 + l15;
    float bs = bias[n];
#pragma unroll
    for (int r = 0; r < 4; r++) {
      int mq = m0 + wid * 16 + quad * 4 + r;
      out[(size_t)mq * C_DIM + n] = acc[c][r] + bs;
    }
  }
}

// ---------------------------------------------------------------------------
extern "C" void kernel_launch(void* const* d_in, const int* in_sizes, int n_in,
                              void* d_out, int out_size, void* d_ws, size_t ws_size,
                              hipStream_t stream) {
  const float* x     = (const float*)d_in[0];
  const float* wq    = (const float*)d_in[1];
  const float* wk    = (const float*)d_in[2];
  const float* wv    = (const float*)d_in[3];
  const float* wproj = (const float*)d_in[4];
  const float* bias  = (const float*)d_in[5];

  short* ws = (short*)d_ws;
  // ws (16M shorts = 32 MB, R4-proven footprint):
  short* wt_qkv = ws;                    // 3,145,728  (48 x 64 x 1024)
  short* wpT    = ws + 3145728;          // 1,048,576
  short* qb     = ws + 4194304;          // 4,194,304  (B,H,T,Dh)
  short* attnb  = ws + 8388608;          // 4,194,304  (B,T,C)
  short* xb     = ws + 12582912;         // 4,194,304  (B*T, C)
  // K and V^T live in d_out (16 MB) until proj overwrites it (stream-serial):
  short* kb     = (short*)d_out;         // 4,194,304  (B,H,T,Dh)
  short* vtb    = (short*)d_out + 4194304; // 4,194,304 (B,H,Dh,T)

  ingest_kernel<<<32768, 256, 0, stream>>>(x, wq, wk, wv, wproj, xb, wt_qkv, wpT);
  qkv_kernel<<<dim3(64, 48), 256, 0, stream>>>(xb, wt_qkv, qb, kb, vtb);
  attn_kernel<<<dim3(32, 16, 2), 256, 0, stream>>>(qb, kb, vtb, attnb);
  proj_kernel<<<dim3(64, 16), 256, 0, stream>>>(attnb, wpT, bias, (float*)d_out);
}

// Round 7
// 508.447 us; speedup vs baseline: 12.9973x; 1.2185x over previous
//
#include <hip/hip_runtime.h>

// MultiHeadAttention: B=2, T=2048, C=1024, H=16, Dh=64, causal, scale = C^-0.5 = 1/32.
// FP32 I/O (proven R5). bf16 MFMA pipeline, fp32 accumulation.
//
//   1. ingest: x->xb bf16; wq/wk/wv (H,C,Dh) -> wt (48,Dh,C) bf16; w_proj -> wpT bf16
//   2. qkv:    Q*scale (ws), K (d_out lo), V^T (d_out hi)  [d_out scratch until proj]
//   3. attn:   flash, S^T orientation (R7): 128 q/block, 32 q/wave, no barriers
//   4. proj:   attnb @ w_proj + bias -> d_out fp32 (overwrites K/V scratch)
//
// ws layout (16M shorts = 32 MB): wt[0,3M) wpT[3M,4M) qb[4M,8M) attnb[8M,12M) xb[12M,16M)
//
// MFMA fragment layouts (HW-verified R6, guide §3):
//   A:   lane holds A[m=lane&15][k=quad*8+j], j=0..7   (quad = lane>>4)
//   B:   lane holds B[k=quad*8+j][n=lane&15]
//   C/D: lane holds D[m=quad*4+r][n=lane&15], r=0..3
// R7 attn trick: compute S^T = K·Q^T (A=K, B=Q; same global addresses as R6).
// Then each lane's 16 scores share ONE q row (n=lane&15): softmax state is a
// per-lane scalar, and P rows are register-consecutive in key -> b64 LDS
// writes / b128 B-frag reads, wave-private, fence-ordered, zero barriers.

typedef unsigned short u16;
typedef unsigned int u32;

using bf16x8 = __attribute__((ext_vector_type(8))) short;
using bf16x4 = __attribute__((ext_vector_type(4))) short;
using f32x4  = __attribute__((ext_vector_type(4))) float;

#define T_SEQ 2048
#define C_DIM 1024
#define H_NUM 16
#define D_HEAD 64

static __device__ inline f32x4 mfma16(bf16x8 a, bf16x8 b, f32x4 c) {
  return __builtin_amdgcn_mfma_f32_16x16x32_bf16(a, b, c, 0, 0, 0);
}

static __device__ inline short f2bf(float f) {
  union { float f; u32 u; } v; v.f = f;
  u32 u = v.u;
  return (short)((u + 0x7FFFu + ((u >> 16) & 1u)) >> 16);
}

// ---------------------------------------------------------------------------
// Kernel 1: ingest fp32 -> bf16 (+ weight transposes). grid 32768 x 256.
__global__ __launch_bounds__(256) void ingest_kernel(
    const float* __restrict__ x, const float* __restrict__ wq,
    const float* __restrict__ wk, const float* __restrict__ wv,
    const float* __restrict__ wproj,
    short* __restrict__ xb, short* __restrict__ wt, short* __restrict__ wpT) {
  long id = (long)blockIdx.x * 256 + threadIdx.x;
  const long NX = 4194304, NW = 7340032;
  if (id < NX) {
    xb[id] = f2bf(x[id]);
  } else if (id < NW) {
    long t = id - NX;
    int h3 = (int)(t >> 16);          // 0..47  (sel*16 + h)
    int r  = (int)(t & 65535);
    int c  = r & 1023;
    int d  = r >> 10;                 // 0..63
    const float* w = (h3 < 16) ? wq : (h3 < 32) ? wk : wv;
    int h = h3 & 15;
    wt[(size_t)h3 * 65536 + d * 1024 + c] = f2bf(w[(size_t)h * 65536 + c * 64 + d]);
  } else {
    long t = id - NW;
    int k = (int)(t & 1023);
    int n = (int)(t >> 10);
    wpT[(size_t)n * 1024 + k] = f2bf(wproj[(size_t)k * 1024 + n]);
  }
}

// ---------------------------------------------------------------------------
// Kernel 2: QKV projection. grid (64, 48), block 256 (4 waves).
// Q is pre-scaled by 1/32 (folds softmax scale; Q only consumed by attn).
__global__ __launch_bounds__(256) void qkv_kernel(
    const short* __restrict__ x, const short* __restrict__ wt,
    short* __restrict__ qo, short* __restrict__ ko, short* __restrict__ vto) {
  const int m0  = blockIdx.x * 64;
  const int by  = blockIdx.y;          // sel*16 + h
  const int tid = threadIdx.x;
  const int wid = tid >> 6;
  const int lane = tid & 63;
  const int l15 = lane & 15, quad = lane >> 4;

  __shared__ __align__(16) short vtile[64 * 65];

  const short* wtp  = wt + (size_t)by * 65536;            // [d][c] layout
  const int  mrow = m0 + wid * 16 + l15;                  // A-frag row
  const short* xrow = x + (size_t)mrow * C_DIM;
  const short* bbase = wtp + (size_t)l15 * C_DIM + quad * 8;

  f32x4 acc[4] = { {0,0,0,0}, {0,0,0,0}, {0,0,0,0}, {0,0,0,0} };

#pragma unroll 4
  for (int kc = 0; kc < C_DIM; kc += 32) {
    bf16x8 a = *(const bf16x8*)(xrow + kc + quad * 8);
#pragma unroll
    for (int c = 0; c < 4; c++) {
      bf16x8 b = *(const bf16x8*)(bbase + (size_t)c * 16 * C_DIM + kc);
      acc[c] = mfma16(a, b, acc[c]);
    }
  }

  const int sel = by >> 4;
  const int h   = by & 15;
  const int b   = m0 >> 11;               // 64-row tiles never straddle b
  const size_t bh = (size_t)(b * H_NUM + h);

  if (sel == 2) {
    // V: stage C-frags in LDS, coalesced transposed store (B,H,Dh,T)
#pragma unroll
    for (int c = 0; c < 4; c++) {
#pragma unroll
      for (int r = 0; r < 4; r++) {
        int ml = wid * 16 + quad * 4 + r;
        vtile[ml * 65 + c * 16 + l15] = f2bf(acc[c][r]);
      }
    }
    __syncthreads();
    int d  = tid >> 2;
    int t0 = (tid & 3) * 16;
    bf16x8 v0, v1;
#pragma unroll
    for (int i = 0; i < 8; i++) {
      v0[i] = vtile[(t0 + i) * 65 + d];
      v1[i] = vtile[(t0 + 8 + i) * 65 + d];
    }
    short* dst = vto + ((bh * D_HEAD + d) * T_SEQ + (m0 & 2047) + t0);
    *(bf16x8*)(dst)     = v0;
    *(bf16x8*)(dst + 8) = v1;
  } else {
    short* outp = (sel == 0) ? qo : ko;   // (B,H,T,Dh)
    const float sc = (sel == 0) ? 0.03125f : 1.0f;
#pragma unroll
    for (int c = 0; c < 4; c++) {
#pragma unroll
      for (int r = 0; r < 4; r++) {
        int t = (m0 & 2047) + wid * 16 + quad * 4 + r;
        int d = c * 16 + l15;
        outp[(bh * T_SEQ + t) * D_HEAD + d] = f2bf(acc[c][r] * sc);
      }
    }
  }
}

// ---------------------------------------------------------------------------
// Kernel 3: flash attention, S^T orientation. grid (16, 16, 2), block 256.
// Block = 128 q rows; wave = 32 q rows (2 halves of 16), fully independent
// (wave-private LDS, no __syncthreads). LPT: qtb = 15 - blockIdx.x.
__global__ __launch_bounds__(256) void attn_kernel(
    const short* __restrict__ q, const short* __restrict__ k,
    const short* __restrict__ vt, short* __restrict__ attn) {
  const int qtb = 15 - blockIdx.x;              // longest blocks dispatch first
  const int h = blockIdx.y, b = blockIdx.z;
  const size_t bh = (size_t)(b * H_NUM + h);
  const short* qp = q  + bh * T_SEQ * D_HEAD;
  const short* kp = k  + bh * T_SEQ * D_HEAD;
  const short* vp = vt + bh * D_HEAD * T_SEQ;   // (Dh, T)

  const int tid = threadIdx.x;
  const int wid = tid >> 6;
  const int lane = tid & 63;
  const int l15 = lane & 15, quad = lane >> 4;

  // P rows: [q_local 0..31][key 0..63 pad to 72] u16; stride 144 B = 16*9 so
  // b128 reads stay 16B-aligned. Write banks: 4(l15%8)+2quad -> 2-way (free).
  __shared__ __align__(16) short P_lds[4][32][72];
  short (*pq)[72] = P_lds[wid];

  const int q0w = qtb * 128 + wid * 32;

  // Q B-frags (B[k=quad*8+j][n=l15] = Q[q0w+h2*16+l15][quad*8+j]), pre-scaled
  bf16x8 qa[2][2];
#pragma unroll
  for (int h2 = 0; h2 < 2; h2++)
#pragma unroll
    for (int c2 = 0; c2 < 2; c2++)
      qa[h2][c2] = *(const bf16x8*)(qp + (size_t)(q0w + h2 * 16 + l15) * D_HEAD
                                    + c2 * 32 + quad * 8);

  f32x4 o[2][4];
#pragma unroll
  for (int h2 = 0; h2 < 2; h2++)
#pragma unroll
    for (int c = 0; c < 4; c++) o[h2][c] = f32x4{0, 0, 0, 0};
  float m_i[2] = { -1e30f, -1e30f };
  float l_i[2] = { 0.f, 0.f };

  const int nt = (q0w + 95) >> 6;   // tiles until this wave's diagonal done

#pragma unroll 1
  for (int t = 0; t < nt; t++) {
    const int s0 = t * 64;

    // S^T = K Q^T: A = K rows (key tiles c), B = Q. s[h2][c][r] =
    // S[q = q0w+h2*16+l15][key = s0+c*16+quad*4+r]
    f32x4 s[2][4];
#pragma unroll
    for (int c = 0; c < 4; c++) {
      const short* krow = kp + (size_t)(s0 + c * 16 + l15) * D_HEAD + quad * 8;
      bf16x8 ka0 = *(const bf16x8*)(krow);
      bf16x8 ka1 = *(const bf16x8*)(krow + 32);
#pragma unroll
      for (int h2 = 0; h2 < 2; h2++) {
        f32x4 z = { 0, 0, 0, 0 };
        z = mfma16(ka0, qa[h2][0], z);
        z = mfma16(ka1, qa[h2][1], z);
        s[h2][c] = z;
      }
    }

    const bool needMask = (s0 + 64 > q0w);   // wave-uniform
#pragma unroll
    for (int h2 = 0; h2 < 2; h2++) {
      const int qg = q0w + h2 * 16 + l15;
      if (needMask) {
#pragma unroll
        for (int c = 0; c < 4; c++)
#pragma unroll
          for (int r = 0; r < 4; r++)
            if (s0 + c * 16 + quad * 4 + r > qg) s[h2][c][r] = -1e30f;
      }
      // row max: 16 in-lane + 2 cross-quad shuffles (lanes same l15)
      float rm = -1e30f;
#pragma unroll
      for (int c = 0; c < 4; c++)
#pragma unroll
        for (int r = 0; r < 4; r++) rm = fmaxf(rm, s[h2][c][r]);
      rm = fmaxf(rm, __shfl_xor(rm, 16));
      rm = fmaxf(rm, __shfl_xor(rm, 32));
      float mn = fmaxf(m_i[h2], rm);
      float alpha = __expf(m_i[h2] - mn);    // exp(-1e30-finite)==0, no NaN
      m_i[h2] = mn;
      float rs = 0.f;
#pragma unroll
      for (int c = 0; c < 4; c++) {
#pragma unroll
        for (int r = 0; r < 4; r++) {
          float p = __expf(s[h2][c][r] - mn);
          s[h2][c][r] = p;
          rs += p;
        }
      }
      rs += __shfl_xor(rs, 16);
      rs += __shfl_xor(rs, 32);
      l_i[h2] = l_i[h2] * alpha + rs;
#pragma unroll
      for (int c = 0; c < 4; c++) {
        o[h2][c][0] *= alpha; o[h2][c][1] *= alpha;
        o[h2][c][2] *= alpha; o[h2][c][3] *= alpha;
      }
      // P write: keys quad*4+r are register-consecutive -> one b64 per tile
#pragma unroll
      for (int c = 0; c < 4; c++) {
        bf16x4 pk;
        pk[0] = f2bf(s[h2][c][0]); pk[1] = f2bf(s[h2][c][1]);
        pk[2] = f2bf(s[h2][c][2]); pk[3] = f2bf(s[h2][c][3]);
        *(bf16x4*)(&pq[h2 * 16 + l15][c * 16 + quad * 4]) = pk;
      }
    }
    // wave-private LDS RAW: DS ops execute in order within a wave; fence stops
    // compiler reordering the reads above the writes.
    asm volatile("" ::: "memory");

    // O^T += V^T P^T: A = V^T d-tiles, B = P rows from LDS (b128, aligned)
#pragma unroll
    for (int kb2 = 0; kb2 < 2; kb2++) {
      bf16x8 pb[2];
      pb[0] = *(const bf16x8*)(&pq[l15][kb2 * 32 + quad * 8]);
      pb[1] = *(const bf16x8*)(&pq[16 + l15][kb2 * 32 + quad * 8]);
#pragma unroll
      for (int c = 0; c < 4; c++) {
        bf16x8 va = *(const bf16x8*)(vp + (size_t)(c * 16 + l15) * T_SEQ
                                     + s0 + kb2 * 32 + quad * 8);
        o[0][c] = mfma16(va, pb[0], o[0][c]);
        o[1][c] = mfma16(va, pb[1], o[1][c]);
      }
    }
    asm volatile("" ::: "memory");   // WAR: next writes stay after these reads
  }

  // epilogue: O^T C-layout: lane holds O[d=c*16+quad*4+r][q=q0w+h2*16+l15];
  // r consecutive in d -> b64 stores. Write concat-head (B,T,H*Dh) bf16.
#pragma unroll
  for (int h2 = 0; h2 < 2; h2++) {
    float inv = 1.0f / l_i[h2];
    int qg = q0w + h2 * 16 + l15;
    size_t rowoff = ((size_t)b * T_SEQ + qg) * C_DIM + h * D_HEAD;
#pragma unroll
    for (int c = 0; c < 4; c++) {
      bf16x4 ok;
      ok[0] = f2bf(o[h2][c][0] * inv); ok[1] = f2bf(o[h2][c][1] * inv);
      ok[2] = f2bf(o[h2][c][2] * inv); ok[3] = f2bf(o[h2][c][3] * inv);
      *(bf16x4*)(&attn[rowoff + c * 16 + quad * 4]) = ok;
    }
  }
}

// ---------------------------------------------------------------------------
// Kernel 4: output projection + fp32 bias -> fp32 out. grid (64, 16).
__global__ __launch_bounds__(256) void proj_kernel(
    const short* __restrict__ a_in, const short* __restrict__ wpT,
    const float* __restrict__ bias, float* __restrict__ out) {
  const int m0 = blockIdx.x * 64, n0 = blockIdx.y * 64;
  const int tid = threadIdx.x;
  const int wid = tid >> 6;
  const int lane = tid & 63;
  const int l15 = lane & 15, quad = lane >> 4;

  const int  mrow = m0 + wid * 16 + l15;
  const short* arow = a_in + (size_t)mrow * C_DIM;
  const short* bbase = wpT + (size_t)(n0 + l15) * C_DIM + quad * 8;

  f32x4 acc[4] = { {0,0,0,0}, {0,0,0,0}, {0,0,0,0}, {0,0,0,0} };

#pragma unroll 4
  for (int kc = 0; kc < C_DIM; kc += 32) {
    bf16x8 a = *(const bf16x8*)(arow + kc + quad * 8);
#pragma unroll
    for (int c = 0; c < 4; c++) {
      bf16x8 b = *(const bf16x8*)(bbase + (size_t)c * 16 * C_DIM + kc);
      acc[c] = mfma16(a, b, acc[c]);
    }
  }

#pragma unroll
  for (int c = 0; c < 4; c++) {
    int n = n0 + c * 16 + l15;
    float bs = bias[n];
#pragma unroll
    for (int r = 0; r < 4; r++) {
      int mq = m0 + wid * 16 + quad * 4 + r;
      out[(size_t)mq * C_DIM + n] = acc[c][r] + bs;
    }
  }
}

// ---------------------------------------------------------------------------
extern "C" void kernel_launch(void* const* d_in, const int* in_sizes, int n_in,
                              void* d_out, int out_size, void* d_ws, size_t ws_size,
                              hipStream_t stream) {
  const float* x     = (const float*)d_in[0];
  const float* wq    = (const float*)d_in[1];
  const float* wk    = (const float*)d_in[2];
  const float* wv    = (const float*)d_in[3];
  const float* wproj = (const float*)d_in[4];
  const float* bias  = (const float*)d_in[5];

  short* ws = (short*)d_ws;
  short* wt_qkv = ws;                      // 3,145,728  (48 x 64 x 1024)
  short* wpT    = ws + 3145728;            // 1,048,576
  short* qb     = ws + 4194304;            // 4,194,304  (B,H,T,Dh), pre-scaled
  short* attnb  = ws + 8388608;            // 4,194,304  (B,T,C)
  short* xb     = ws + 12582912;           // 4,194,304  (B*T, C)
  // K and V^T live in d_out (16 MB) until proj overwrites it (stream-serial):
  short* kb     = (short*)d_out;           // 4,194,304  (B,H,T,Dh)
  short* vtb    = (short*)d_out + 4194304; // 4,194,304  (B,H,Dh,T)

  ingest_kernel<<<32768, 256, 0, stream>>>(x, wq, wk, wv, wproj, xb, wt_qkv, wpT);
  qkv_kernel<<<dim3(64, 48), 256, 0, stream>>>(xb, wt_qkv, qb, kb, vtb);
  attn_kernel<<<dim3(16, 16, 2), 256, 0, stream>>>(qb, kb, vtb, attnb);
  proj_kernel<<<dim3(64, 16), 256, 0, stream>>>(attnb, wpT, bias, (float*)d_out);
}

// Round 8
// 301.905 us; speedup vs baseline: 21.8892x; 1.6841x over previous
//
#include <hip/hip_runtime.h>

// MultiHeadAttention: B=2, T=2048, C=1024, H=16, Dh=64, causal, scale = C^-0.5 = 1/32.
// FP32 I/O (proven R5). bf16 MFMA pipeline, fp32 accumulation.
//
//   1. ingest: x->xb bf16; wq/wk/wv (H,C,Dh) -> wt (48,Dh,C) bf16; w_proj -> wpT bf16
//   2. qkv:    m97-style 128x128 GEMM (global_load_lds staging). Q*scale, K,
//              and V^T-direct (operand-swap trick) epilogues.
//   3. attn:   flash, S^T orientation (R7-proven): 128 q/block, 32 q/wave, no barriers
//   4. proj:   same m97 GEMM core, bias + fp32 out -> d_out
//
// ws layout (16M shorts = 32 MB): wt[0,3M) wpT[3M,4M) qb[4M,8M) attnb[8M,12M) xb[12M,16M)
// K and V^T live in d_out (16 MB scratch) until proj overwrites it.
//
// MFMA fragment layouts (HW-verified R6/R7):
//   A:   lane holds A[m=lane&15][k=quad*8+j], j=0..7   (quad = lane>>4)
//   B:   lane holds B[k=quad*8+j][n=lane&15]
//   C/D: lane holds D[m=quad*4+r][n=lane&15], r=0..3
// V^T trick: for V column-blocks, compute D = Wv^T(A) x X^T(B): A-frags read
// from the Bs tile, B-frags from the As tile (identical addresses, swapped
// roles) -> C-layout directly holds V^T[d][t]; epilogue symmetric to Q/K.

typedef unsigned short u16;
typedef unsigned int u32;

using bf16x8 = __attribute__((ext_vector_type(8))) short;
using bf16x4 = __attribute__((ext_vector_type(4))) short;
using f32x4  = __attribute__((ext_vector_type(4))) float;

#define T_SEQ 2048
#define C_DIM 1024
#define H_NUM 16
#define D_HEAD 64

static __device__ inline f32x4 mfma16(bf16x8 a, bf16x8 b, f32x4 c) {
  return __builtin_amdgcn_mfma_f32_16x16x32_bf16(a, b, c, 0, 0, 0);
}

static __device__ inline short f2bf(float f) {
  union { float f; u32 u; } v; v.f = f;
  u32 u = v.u;
  return (short)((u + 0x7FFFu + ((u >> 16) & 1u)) >> 16);
}

// async global->LDS, 16B per lane; LDS dst = wave-uniform base + lane*16
static __device__ inline void gload_lds16(const short* g, short* l) {
  __builtin_amdgcn_global_load_lds(
      (const __attribute__((address_space(1))) unsigned int*)g,
      (__attribute__((address_space(3))) unsigned int*)l,
      16, 0, 0);
}

// ---------------------------------------------------------------------------
// Kernel 1: ingest fp32 -> bf16 (+ weight transposes). grid 32768 x 256.
__global__ __launch_bounds__(256) void ingest_kernel(
    const float* __restrict__ x, const float* __restrict__ wq,
    const float* __restrict__ wk, const float* __restrict__ wv,
    const float* __restrict__ wproj,
    short* __restrict__ xb, short* __restrict__ wt, short* __restrict__ wpT) {
  long id = (long)blockIdx.x * 256 + threadIdx.x;
  const long NX = 4194304, NW = 7340032;
  if (id < NX) {
    xb[id] = f2bf(x[id]);
  } else if (id < NW) {
    long t = id - NX;
    int h3 = (int)(t >> 16);          // 0..47  (sel*16 + h)
    int r  = (int)(t & 65535);
    int c  = r & 1023;
    int d  = r >> 10;                 // 0..63
    const float* w = (h3 < 16) ? wq : (h3 < 32) ? wk : wv;
    int h = h3 & 15;
    wt[(size_t)h3 * 65536 + d * 1024 + c] = f2bf(w[(size_t)h * 65536 + c * 64 + d]);
  } else {
    long t = id - NW;
    int k = (int)(t & 1023);
    int n = (int)(t >> 10);
    wpT[(size_t)n * 1024 + k] = f2bf(wproj[(size_t)k * 1024 + n]);
  }
}

// ---------------------------------------------------------------------------
// Kernel 2: QKV GEMM, m97 structure. grid (32 m-tiles, 24 n-tiles), 256 thr.
// Block: 128x128; wave (wm,wn): 64x64 = 4x4 C-frags. BK=32, 32 K-steps.
// Staging: wave w stages rows [w*32,w*32+32) of As and Bs via 2x2
// global_load_lds (16B/lane; 16 rows x 64B per instruction).
__global__ __launch_bounds__(256) void qkv_kernel(
    const short* __restrict__ x, const short* __restrict__ wt,
    short* __restrict__ qo, short* __restrict__ ko, short* __restrict__ vto) {
  const int m0 = blockIdx.x * 128;
  const int n0 = blockIdx.y * 128;
  const int tid = threadIdx.x, w = tid >> 6, lane = tid & 63;
  const int l15 = lane & 15, quad = lane >> 4;
  const int wm = w >> 1, wn = w & 1;

  __shared__ __align__(16) short As[128 * 32];
  __shared__ __align__(16) short Bs[128 * 32];

  const int srow = w * 32 + (lane >> 2);
  const int skof = (lane & 3) * 8;
  const short* ga0 = x  + (size_t)(m0 + srow) * 1024 + skof;
  const short* ga1 = ga0 + 16 * 1024;
  const short* gb0 = wt + (size_t)(n0 + srow) * 1024 + skof;
  const short* gb1 = gb0 + 16 * 1024;
  short* la0 = As + (w * 32) * 32;
  short* la1 = As + (w * 32 + 16) * 32;
  short* lb0 = Bs + (w * 32) * 32;
  short* lb1 = Bs + (w * 32 + 16) * 32;

  const short* ard = As + (wm * 64 + l15) * 32 + quad * 8;   // +mi*16*32
  const short* brd = Bs + (wn * 64 + l15) * 32 + quad * 8;   // +ni*16*32

  f32x4 acc[4][4];
#pragma unroll
  for (int i = 0; i < 4; i++)
#pragma unroll
    for (int j = 0; j < 4; j++) acc[i][j] = f32x4{0, 0, 0, 0};

  const bool isv = (n0 >= 2048);   // V column-blocks: operand-swap mode

#pragma unroll 1
  for (int kt = 0; kt < 32; kt++) {
    const int k0 = kt * 32;
    gload_lds16(ga0 + k0, la0);
    gload_lds16(ga1 + k0, la1);
    gload_lds16(gb0 + k0, lb0);
    gload_lds16(gb1 + k0, lb1);
    __syncthreads();

    bf16x8 af[4], bfr[4];
#pragma unroll
    for (int i = 0; i < 4; i++) {
      af[i]  = *(const bf16x8*)(ard + i * 16 * 32);
      bfr[i] = *(const bf16x8*)(brd + i * 16 * 32);
    }
    if (!isv) {
#pragma unroll
      for (int mi = 0; mi < 4; mi++)
#pragma unroll
        for (int ni = 0; ni < 4; ni++)
          acc[mi][ni] = mfma16(af[mi], bfr[ni], acc[mi][ni]);
    } else {
      // D[d][t]: A = Wv rows (Bs), B = X rows (As)
#pragma unroll
      for (int ni = 0; ni < 4; ni++)
#pragma unroll
        for (int mi = 0; mi < 4; mi++)
          acc[ni][mi] = mfma16(bfr[ni], af[mi], acc[ni][mi]);
    }
    __syncthreads();
  }

  const int chunk = (n0 >> 6) + wn;     // 0..47 = sel*16 + h
  const int sel = chunk >> 4, h = chunk & 15;
  if (!isv) {
    short* outp = (sel == 0) ? qo : ko;   // (B,H,T,Dh)
    const float sc = (sel == 0) ? 0.03125f : 1.0f;   // fold softmax scale
#pragma unroll
    for (int mi = 0; mi < 4; mi++) {
#pragma unroll
      for (int r = 0; r < 4; r++) {
        int tg = m0 + wm * 64 + mi * 16 + quad * 4 + r;
        int b = tg >> 11, tl = tg & 2047;
        size_t rowb = ((size_t)(b * H_NUM + h) * T_SEQ + tl) * D_HEAD;
#pragma unroll
        for (int ni = 0; ni < 4; ni++)
          outp[rowb + ni * 16 + l15] = f2bf(acc[mi][ni][r] * sc);
      }
    }
  } else {
    // acc[ni][mi] holds V^T[d = ni*16+quad*4+r][t = m0+wm*64+mi*16+l15]
#pragma unroll
    for (int ni = 0; ni < 4; ni++) {
#pragma unroll
      for (int r = 0; r < 4; r++) {
        int d = ni * 16 + quad * 4 + r;
#pragma unroll
        for (int mi = 0; mi < 4; mi++) {
          int tg = m0 + wm * 64 + mi * 16 + l15;
          int b = tg >> 11, tl = tg & 2047;
          vto[((size_t)(b * H_NUM + h) * D_HEAD + d) * T_SEQ + tl] =
              f2bf(acc[ni][mi][r]);
        }
      }
    }
  }
}

// ---------------------------------------------------------------------------
// Kernel 3: flash attention, S^T orientation (R7-proven). grid (16, 16, 2).
__global__ __launch_bounds__(256) void attn_kernel(
    const short* __restrict__ q, const short* __restrict__ k,
    const short* __restrict__ vt, short* __restrict__ attn) {
  const int qtb = 15 - blockIdx.x;              // LPT: longest first
  const int h = blockIdx.y, b = blockIdx.z;
  const size_t bh = (size_t)(b * H_NUM + h);
  const short* qp = q  + bh * T_SEQ * D_HEAD;
  const short* kp = k  + bh * T_SEQ * D_HEAD;
  const short* vp = vt + bh * D_HEAD * T_SEQ;   // (Dh, T)

  const int tid = threadIdx.x;
  const int wid = tid >> 6;
  const int lane = tid & 63;
  const int l15 = lane & 15, quad = lane >> 4;

  __shared__ __align__(16) short P_lds[4][32][72];
  short (*pq)[72] = P_lds[wid];

  const int q0w = qtb * 128 + wid * 32;

  bf16x8 qa[2][2];
#pragma unroll
  for (int h2 = 0; h2 < 2; h2++)
#pragma unroll
    for (int c2 = 0; c2 < 2; c2++)
      qa[h2][c2] = *(const bf16x8*)(qp + (size_t)(q0w + h2 * 16 + l15) * D_HEAD
                                    + c2 * 32 + quad * 8);

  f32x4 o[2][4];
#pragma unroll
  for (int h2 = 0; h2 < 2; h2++)
#pragma unroll
    for (int c = 0; c < 4; c++) o[h2][c] = f32x4{0, 0, 0, 0};
  float m_i[2] = { -1e30f, -1e30f };
  float l_i[2] = { 0.f, 0.f };

  const int nt = (q0w + 95) >> 6;

#pragma unroll 1
  for (int t = 0; t < nt; t++) {
    const int s0 = t * 64;

    f32x4 s[2][4];
#pragma unroll
    for (int c = 0; c < 4; c++) {
      const short* krow = kp + (size_t)(s0 + c * 16 + l15) * D_HEAD + quad * 8;
      bf16x8 ka0 = *(const bf16x8*)(krow);
      bf16x8 ka1 = *(const bf16x8*)(krow + 32);
#pragma unroll
      for (int h2 = 0; h2 < 2; h2++) {
        f32x4 z = { 0, 0, 0, 0 };
        z = mfma16(ka0, qa[h2][0], z);
        z = mfma16(ka1, qa[h2][1], z);
        s[h2][c] = z;
      }
    }

    const bool needMask = (s0 + 64 > q0w);
#pragma unroll
    for (int h2 = 0; h2 < 2; h2++) {
      const int qg = q0w + h2 * 16 + l15;
      if (needMask) {
#pragma unroll
        for (int c = 0; c < 4; c++)
#pragma unroll
          for (int r = 0; r < 4; r++)
            if (s0 + c * 16 + quad * 4 + r > qg) s[h2][c][r] = -1e30f;
      }
      float rm = -1e30f;
#pragma unroll
      for (int c = 0; c < 4; c++)
#pragma unroll
        for (int r = 0; r < 4; r++) rm = fmaxf(rm, s[h2][c][r]);
      rm = fmaxf(rm, __shfl_xor(rm, 16));
      rm = fmaxf(rm, __shfl_xor(rm, 32));
      float mn = fmaxf(m_i[h2], rm);
      float alpha = __expf(m_i[h2] - mn);
      m_i[h2] = mn;
      float rs = 0.f;
#pragma unroll
      for (int c = 0; c < 4; c++) {
#pragma unroll
        for (int r = 0; r < 4; r++) {
          float p = __expf(s[h2][c][r] - mn);
          s[h2][c][r] = p;
          rs += p;
        }
      }
      rs += __shfl_xor(rs, 16);
      rs += __shfl_xor(rs, 32);
      l_i[h2] = l_i[h2] * alpha + rs;
#pragma unroll
      for (int c = 0; c < 4; c++) {
        o[h2][c][0] *= alpha; o[h2][c][1] *= alpha;
        o[h2][c][2] *= alpha; o[h2][c][3] *= alpha;
      }
#pragma unroll
      for (int c = 0; c < 4; c++) {
        bf16x4 pk;
        pk[0] = f2bf(s[h2][c][0]); pk[1] = f2bf(s[h2][c][1]);
        pk[2] = f2bf(s[h2][c][2]); pk[3] = f2bf(s[h2][c][3]);
        *(bf16x4*)(&pq[h2 * 16 + l15][c * 16 + quad * 4]) = pk;
      }
    }
    asm volatile("" ::: "memory");

#pragma unroll
    for (int kb2 = 0; kb2 < 2; kb2++) {
      bf16x8 pb[2];
      pb[0] = *(const bf16x8*)(&pq[l15][kb2 * 32 + quad * 8]);
      pb[1] = *(const bf16x8*)(&pq[16 + l15][kb2 * 32 + quad * 8]);
#pragma unroll
      for (int c = 0; c < 4; c++) {
        bf16x8 va = *(const bf16x8*)(vp + (size_t)(c * 16 + l15) * T_SEQ
                                     + s0 + kb2 * 32 + quad * 8);
        o[0][c] = mfma16(va, pb[0], o[0][c]);
        o[1][c] = mfma16(va, pb[1], o[1][c]);
      }
    }
    asm volatile("" ::: "memory");
  }

#pragma unroll
  for (int h2 = 0; h2 < 2; h2++) {
    float inv = 1.0f / l_i[h2];
    int qg = q0w + h2 * 16 + l15;
    size_t rowoff = ((size_t)b * T_SEQ + qg) * C_DIM + h * D_HEAD;
#pragma unroll
    for (int c = 0; c < 4; c++) {
      bf16x4 ok;
      ok[0] = f2bf(o[h2][c][0] * inv); ok[1] = f2bf(o[h2][c][1] * inv);
      ok[2] = f2bf(o[h2][c][2] * inv); ok[3] = f2bf(o[h2][c][3] * inv);
      *(bf16x4*)(&attn[rowoff + c * 16 + quad * 4]) = ok;
    }
  }
}

// ---------------------------------------------------------------------------
// Kernel 4: output projection, m97 structure. grid (32, 8). fp32 out + bias.
__global__ __launch_bounds__(256) void proj_kernel(
    const short* __restrict__ a_in, const short* __restrict__ wpT,
    const float* __restrict__ bias, float* __restrict__ out) {
  const int m0 = blockIdx.x * 128;
  const int n0 = blockIdx.y * 128;
  const int tid = threadIdx.x, w = tid >> 6, lane = tid & 63;
  const int l15 = lane & 15, quad = lane >> 4;
  const int wm = w >> 1, wn = w & 1;

  __shared__ __align__(16) short As[128 * 32];
  __shared__ __align__(16) short Bs[128 * 32];

  const int srow = w * 32 + (lane >> 2);
  const int skof = (lane & 3) * 8;
  const short* ga0 = a_in + (size_t)(m0 + srow) * 1024 + skof;
  const short* ga1 = ga0 + 16 * 1024;
  const short* gb0 = wpT + (size_t)(n0 + srow) * 1024 + skof;
  const short* gb1 = gb0 + 16 * 1024;
  short* la0 = As + (w * 32) * 32;
  short* la1 = As + (w * 32 + 16) * 32;
  short* lb0 = Bs + (w * 32) * 32;
  short* lb1 = Bs + (w * 32 + 16) * 32;

  const short* ard = As + (wm * 64 + l15) * 32 + quad * 8;
  const short* brd = Bs + (wn * 64 + l15) * 32 + quad * 8;

  f32x4 acc[4][4];
#pragma unroll
  for (int i = 0; i < 4; i++)
#pragma unroll
    for (int j = 0; j < 4; j++) acc[i][j] = f32x4{0, 0, 0, 0};

#pragma unroll 1
  for (int kt = 0; kt < 32; kt++) {
    const int k0 = kt * 32;
    gload_lds16(ga0 + k0, la0);
    gload_lds16(ga1 + k0, la1);
    gload_lds16(gb0 + k0, lb0);
    gload_lds16(gb1 + k0, lb1);
    __syncthreads();

    bf16x8 af[4], bfr[4];
#pragma unroll
    for (int i = 0; i < 4; i++) {
      af[i]  = *(const bf16x8*)(ard + i * 16 * 32);
      bfr[i] = *(const bf16x8*)(brd + i * 16 * 32);
    }
#pragma unroll
    for (int mi = 0; mi < 4; mi++)
#pragma unroll
      for (int ni = 0; ni < 4; ni++)
        acc[mi][ni] = mfma16(af[mi], bfr[ni], acc[mi][ni]);
    __syncthreads();
  }

#pragma unroll
  for (int mi = 0; mi < 4; mi++) {
#pragma unroll
    for (int r = 0; r < 4; r++) {
      int mq = m0 + wm * 64 + mi * 16 + quad * 4 + r;
#pragma unroll
      for (int ni = 0; ni < 4; ni++) {
        int n = n0 + wn * 64 + ni * 16 + l15;
        out[(size_t)mq * C_DIM + n] = acc[mi][ni][r] + bias[n];
      }
    }
  }
}

// ---------------------------------------------------------------------------
extern "C" void kernel_launch(void* const* d_in, const int* in_sizes, int n_in,
                              void* d_out, int out_size, void* d_ws, size_t ws_size,
                              hipStream_t stream) {
  const float* x     = (const float*)d_in[0];
  const float* wq    = (const float*)d_in[1];
  const float* wk    = (const float*)d_in[2];
  const float* wv    = (const float*)d_in[3];
  const float* wproj = (const float*)d_in[4];
  const float* bias  = (const float*)d_in[5];

  short* ws = (short*)d_ws;
  short* wt_qkv = ws;                      // 3,145,728  (48 x 64 x 1024)
  short* wpT    = ws + 3145728;            // 1,048,576
  short* qb     = ws + 4194304;            // 4,194,304  (B,H,T,Dh), pre-scaled
  short* attnb  = ws + 8388608;            // 4,194,304  (B,T,C)
  short* xb     = ws + 12582912;           // 4,194,304  (B*T, C)
  short* kb     = (short*)d_out;           // 4,194,304  (B,H,T,Dh)
  short* vtb    = (short*)d_out + 4194304; // 4,194,304  (B,H,Dh,T)

  ingest_kernel<<<32768, 256, 0, stream>>>(x, wq, wk, wv, wproj, xb, wt_qkv, wpT);
  qkv_kernel<<<dim3(32, 24), 256, 0, stream>>>(xb, wt_qkv, qb, kb, vtb);
  attn_kernel<<<dim3(16, 16, 2), 256, 0, stream>>>(qb, kb, vtb, attnb);
  proj_kernel<<<dim3(32, 8), 256, 0, stream>>>(attnb, wpT, bias, (float*)d_out);
}